// Round 9
// baseline (440.405 us; speedup 1.0000x reference)
//
#include <hip/hip_runtime.h>

#define N_NODESC 50000
#define N_EDGESC 640000
#define N_GRAPHSC 64
#define HIDC 128
#define LN_EPSF 1e-5f
#define POOL_SPLIT 16
#define SCAN_NB 49   // 49*1024 = 50176 >= 50000
#define EGRID ((N_EDGESC + 255) / 256)
#define NGRID_GB ((N_NODESC + 255) / 256)

typedef short bf16x8 __attribute__((ext_vector_type(8)));
typedef float f32x4 __attribute__((ext_vector_type(4)));

// ---------- helpers ----------
static __device__ __forceinline__ unsigned ord_enc(float f) {
  unsigned u = __float_as_uint(f);
  return (u & 0x80000000u) ? ~u : (u | 0x80000000u);
}
static __device__ __forceinline__ float ord_dec(unsigned u) {
  return __uint_as_float((u & 0x80000000u) ? (u ^ 0x80000000u) : ~u);
}
static __device__ __forceinline__ unsigned short f2bf(float x) {
  unsigned u = __float_as_uint(x);
  u += 0x7fffu + ((u >> 16) & 1u);
  return (unsigned short)(u >> 16);
}
static __device__ __forceinline__ float bf2f(unsigned short b) {
  return __uint_as_float(((unsigned)b) << 16);
}

static __device__ __forceinline__ void mlp16(float in0, float in1, float in2,
    const float* __restrict__ W1, const float* __restrict__ b1,
    const float* __restrict__ g, const float* __restrict__ be,
    const float* __restrict__ W2, const float* __restrict__ b2,
    float* __restrict__ out) {
  float h[16];
  float s1 = 0.f, s2 = 0.f;
#pragma unroll
  for (int j = 0; j < 16; ++j) {
    float v = b1[j] + W1[j*3+0]*in0 + W1[j*3+1]*in1 + W1[j*3+2]*in2;
    v = fmaxf(v, 0.f);
    h[j] = v; s1 += v; s2 += v*v;
  }
  float mu = s1 * (1.f/16.f);
  float var = fmaxf(s2 * (1.f/16.f) - mu*mu, 0.f);
  float rs = rsqrtf(var + LN_EPSF);
  float z[16];
#pragma unroll
  for (int j = 0; j < 16; ++j) z[j] = (h[j]-mu)*rs*g[j] + be[j];
#pragma unroll
  for (int j = 0; j < 16; ++j) {
    float v = b2[j];
#pragma unroll
    for (int k = 0; k < 16; ++k) v += W2[j*16+k]*z[k];
    out[j] = v;
  }
}

// ---------- weight pre-conversion fp32 -> bf16 (all-block-constant matrices) ----------
__global__ __launch_bounds__(256) void wprep_kernel(
    const float* __restrict__ cW1, const float* __restrict__ cW2,
    const float* __restrict__ gW1,
    unsigned short* __restrict__ Wb1, unsigned short* __restrict__ Wb2,
    unsigned short* __restrict__ gWb) {
  int i = blockIdx.x * 256 + threadIdx.x;
  if (i < 49152) Wb1[i] = f2bf(cW1[i]);
  else if (i < 98304) Wb2[i - 49152] = f2bf(cW2[i - 49152]);
  else if (i < 106496) gWb[i - 98304] = f2bf(gW1[i - 98304]);
}

// ---------- hist (edges) + gbound (nodes) in one dispatch ----------
__global__ __launch_bounds__(256) void hist_gbound_kernel(const int* __restrict__ ei,
    int* __restrict__ deg, const int* __restrict__ batch, int* __restrict__ gstart) {
  const int b = blockIdx.x;
  if (b < EGRID) {
    int e = b * 256 + threadIdx.x;
    if (e < N_EDGESC) atomicAdd(&deg[ei[N_EDGESC + e]], 1);
  } else {
    int i = (b - EGRID) * 256 + threadIdx.x;
    if (i >= N_NODESC) return;
    int bb = batch[i];
    int prev = (i == 0) ? -1 : batch[i-1];
    for (int g = prev + 1; g <= bb; ++g) gstart[g] = i;
    if (i == N_NODESC - 1) {
      for (int g = bb + 1; g <= N_GRAPHSC; ++g) gstart[g] = N_NODESC;
    }
  }
}

// ---------- scan phase 1 ----------
__global__ __launch_bounds__(1024) void scan1_kernel(const int* __restrict__ deg,
                                                     int* __restrict__ incl,
                                                     int* __restrict__ bsum) {
  const int b = blockIdx.x, t = threadIdx.x;
  const int i = b * 1024 + t;
  const int lane = t & 63, w = t >> 6;
  int v = (i < N_NODESC) ? deg[i] : 0;
#pragma unroll
  for (int off = 1; off < 64; off <<= 1) {
    int n = __shfl_up(v, off);
    if (lane >= off) v += n;
  }
  __shared__ int wsum[16];
  if (lane == 63) wsum[w] = v;
  __syncthreads();
  if (t == 0) {
    int run = 0;
#pragma unroll
    for (int k = 0; k < 16; ++k) { int x = wsum[k]; wsum[k] = run; run += x; }
  }
  __syncthreads();
  v += wsum[w];
  if (i < N_NODESC) incl[i] = v;
  if (t == 1023) bsum[b] = v;
}

// ---------- scan phases 2+3 fused ----------
__global__ __launch_bounds__(1024) void scan23_kernel(const int* __restrict__ deg,
                                                      const int* __restrict__ bsum,
                                                      int* __restrict__ rowptr,
                                                      int* __restrict__ cursor) {
  __shared__ int ex[SCAN_NB + 1];
  const int b = blockIdx.x, t = threadIdx.x;
  if (t < 64) {
    int v = (t < SCAN_NB) ? bsum[t] : 0;
    const int orig = v;
#pragma unroll
    for (int off = 1; off < 64; off <<= 1) {
      int n = __shfl_up(v, off);
      if (t >= off) v += n;
    }
    if (t < SCAN_NB) ex[t] = v - orig;
    if (t == SCAN_NB - 1) ex[SCAN_NB] = v;
  }
  __syncthreads();
  const int i = b * 1024 + t;
  if (i < N_NODESC) {
    int excl = rowptr[i] - deg[i] + ex[b];
    rowptr[i] = excl;
    cursor[i] = excl;
  }
  if (b == 0 && t == 0) rowptr[N_NODESC] = ex[SCAN_NB];
}

__global__ __launch_bounds__(256) void scatter_kernel(const int* __restrict__ ei,
                                                      int* __restrict__ cursor,
                                                      int* __restrict__ esrc) {
  int e = blockIdx.x * 256 + threadIdx.x;
  if (e < N_EDGESC) {
    int d = ei[N_EDGESC + e];
    int slot = atomicAdd(&cursor[d], 1);
    esrc[slot] = ei[e];
  }
}

// ---------- encoder ----------
__global__ __launch_bounds__(128) void enc_kernel(
    const float* __restrict__ x,
    const float* __restrict__ aW1, const float* __restrict__ ab1,
    const float* __restrict__ ag,  const float* __restrict__ abe,
    const float* __restrict__ aW2, const float* __restrict__ ab2,
    const float* __restrict__ oW1, const float* __restrict__ ob1,
    const float* __restrict__ og,  const float* __restrict__ obe,
    const float* __restrict__ oW2, const float* __restrict__ ob2,
    const float* __restrict__ ninW, const float* __restrict__ ninb,
    unsigned short* __restrict__ Hb) {
  __shared__ float sa[48*68];
  __shared__ float sw[48*132];
  const int t = threadIdx.x;
  const int lane = t & 63, w = t >> 6;
  const int nb = blockIdx.x * 64;

  if (t < 64) {
    float in45[45];
    const int gn = nb + t;
    if (gn < N_NODESC) {
      const float* xr = x + gn * 19;
#pragma unroll
      for (int k = 0; k < 9; ++k) in45[k] = xr[k];
#pragma unroll
      for (int k = 0; k < 4; ++k) in45[9+k] = xr[15+k];
      mlp16(xr[9], xr[10], xr[11], aW1, ab1, ag, abe, aW2, ab2, &in45[13]);
      mlp16(xr[12], xr[13], xr[14], oW1, ob1, og, obe, oW2, ob2, &in45[29]);
    } else {
#pragma unroll
      for (int k = 0; k < 45; ++k) in45[k] = 0.f;
    }
#pragma unroll
    for (int k = 0; k < 45; ++k) sa[k*68 + t] = in45[k];
#pragma unroll
    for (int k = 45; k < 48; ++k) sa[k*68 + t] = 0.f;
  }
  for (int idx = t; idx < 48*128; idx += 128) {
    int k = idx >> 7, f = idx & 127;
    sw[k*132 + f] = (k < 45) ? ninW[f*45 + k] : 0.f;
  }
  __syncthreads();

  const int n0 = (lane & 7) * 8;
  const int f0 = ((lane >> 3) << 3) + w * 64;
  float acc[8][8];
#pragma unroll
  for (int i = 0; i < 8; ++i)
#pragma unroll
    for (int j = 0; j < 8; ++j) acc[i][j] = 0.f;

#pragma unroll 4
  for (int k = 0; k < 48; ++k) {
    float av[8], wv[8];
    float4 a0 = *(const float4*)&sa[k*68 + n0];
    float4 a1 = *(const float4*)&sa[k*68 + n0 + 4];
    float4 w0 = *(const float4*)&sw[k*132 + f0];
    float4 w1 = *(const float4*)&sw[k*132 + f0 + 4];
    av[0]=a0.x; av[1]=a0.y; av[2]=a0.z; av[3]=a0.w;
    av[4]=a1.x; av[5]=a1.y; av[6]=a1.z; av[7]=a1.w;
    wv[0]=w0.x; wv[1]=w0.y; wv[2]=w0.z; wv[3]=w0.w;
    wv[4]=w1.x; wv[5]=w1.y; wv[6]=w1.z; wv[7]=w1.w;
#pragma unroll
    for (int i = 0; i < 8; ++i)
#pragma unroll
      for (int j = 0; j < 8; ++j) acc[i][j] += av[i]*wv[j];
  }
  float bb[8];
#pragma unroll
  for (int j = 0; j < 8; ++j) bb[j] = ninb[f0+j];
#pragma unroll
  for (int i = 0; i < 8; ++i) {
    int gn = nb + n0 + i;
    if (gn < N_NODESC) {
      bf16x8 o8;
#pragma unroll
      for (int j = 0; j < 8; ++j) o8[j] = (short)f2bf(acc[i][j] + bb[j]);
      *(bf16x8*)&Hb[gn*HIDC + f0] = o8;
    }
  }
}

// ---------- fused conv layer: gather + GEMM1 + LN + GEMM2 + LN + resid ----------
// B fragments read directly from global bf16 W (L1/L2-resident, all-block constant).
// LDS = A tile only (17.4 KB) -> ~6 blocks/CU for gather latency hiding.
__global__ __launch_bounds__(256, 6) void conv_fused_kernel(
    const unsigned short* __restrict__ Hin,
    const int* __restrict__ rowptr, const int* __restrict__ esrc,
    const float* __restrict__ epsp,
    const unsigned short* __restrict__ W1b, const float* __restrict__ b1,
    const float* __restrict__ g1, const float* __restrict__ be1,
    const unsigned short* __restrict__ W2b, const float* __restrict__ b2,
    const float* __restrict__ lng, const float* __restrict__ lnb,
    unsigned short* __restrict__ Hout) {
  __shared__ unsigned short Ab[64*136];   // M tile, then T tile, then OUT tile
  const int t = threadIdx.x;
  const int nb = blockIdx.x * 64;

  // gather: M = (1+eps)*Hin[node] + sum Hin[src]; 4 lanes/node, all 64 nodes live
  {
    const float e1 = 1.0f + epsp[0];
    const int v64 = t >> 2;         // node 0..63
    const int c   = t & 3;          // chunk group: chunks c*4 .. c*4+3
    const int node = nb + v64;
    if (node < N_NODESC) {
      const unsigned short* __restrict__ hrow = &Hin[node*HIDC + c*32];
      float acc[4][8];
#pragma unroll
      for (int j = 0; j < 4; ++j)
#pragma unroll
        for (int k = 0; k < 8; ++k) acc[j][k] = 0.f;
      int s = rowptr[node];
      const int e = rowptr[node+1];
      for (; s + 2 <= e; s += 2) {
        int i0 = esrc[s], i1 = esrc[s+1];
        const unsigned short* r0 = &Hin[i0*HIDC + c*32];
        const unsigned short* r1 = &Hin[i1*HIDC + c*32];
        bf16x8 x00 = *(const bf16x8*)&r0[0],  x01 = *(const bf16x8*)&r0[8];
        bf16x8 x02 = *(const bf16x8*)&r0[16], x03 = *(const bf16x8*)&r0[24];
        bf16x8 x10 = *(const bf16x8*)&r1[0],  x11 = *(const bf16x8*)&r1[8];
        bf16x8 x12 = *(const bf16x8*)&r1[16], x13 = *(const bf16x8*)&r1[24];
#pragma unroll
        for (int k = 0; k < 8; ++k) {
          acc[0][k] += bf2f((unsigned short)x00[k]) + bf2f((unsigned short)x10[k]);
          acc[1][k] += bf2f((unsigned short)x01[k]) + bf2f((unsigned short)x11[k]);
          acc[2][k] += bf2f((unsigned short)x02[k]) + bf2f((unsigned short)x12[k]);
          acc[3][k] += bf2f((unsigned short)x03[k]) + bf2f((unsigned short)x13[k]);
        }
      }
      if (s < e) {
        const unsigned short* r0 = &Hin[esrc[s]*HIDC + c*32];
        bf16x8 x00 = *(const bf16x8*)&r0[0],  x01 = *(const bf16x8*)&r0[8];
        bf16x8 x02 = *(const bf16x8*)&r0[16], x03 = *(const bf16x8*)&r0[24];
#pragma unroll
        for (int k = 0; k < 8; ++k) {
          acc[0][k] += bf2f((unsigned short)x00[k]);
          acc[1][k] += bf2f((unsigned short)x01[k]);
          acc[2][k] += bf2f((unsigned short)x02[k]);
          acc[3][k] += bf2f((unsigned short)x03[k]);
        }
      }
#pragma unroll
      for (int j = 0; j < 4; ++j) {
        bf16x8 h = *(const bf16x8*)&hrow[j*8];
        bf16x8 m8;
#pragma unroll
        for (int k = 0; k < 8; ++k)
          m8[k] = (short)f2bf(e1*bf2f((unsigned short)h[k]) + acc[j][k]);
        *(bf16x8*)&Ab[v64*136 + c*32 + j*8] = m8;
      }
    } else {
#pragma unroll
      for (int j = 0; j < 4; ++j)
        *(bf16x8*)&Ab[v64*136 + c*32 + j*8] = (bf16x8){0,0,0,0,0,0,0,0};
    }
  }
  __syncthreads();

  const int lane = t & 63, wv = t >> 6;
  const int quad = lane >> 4, l16 = lane & 15;
  const int arow = (wv*16 + l16)*136 + quad*8;
  const int brow_base = l16*HIDC + quad*8;   // + ft*16*HIDC + ks*32

  // MFMA loop 1: M @ W1^T  (B from global)
  f32x4 acc[8];
#pragma unroll
  for (int ft = 0; ft < 8; ++ft) acc[ft] = (f32x4){0.f,0.f,0.f,0.f};
#pragma unroll
  for (int ks = 0; ks < 4; ++ks) {
    bf16x8 a = *(const bf16x8*)(const void*)&Ab[arow + ks*32];
#pragma unroll
    for (int ft = 0; ft < 8; ++ft) {
      bf16x8 b = *(const bf16x8*)&W1b[brow_base + ft*16*HIDC + ks*32];
      acc[ft] = __builtin_amdgcn_mfma_f32_16x16x32_bf16(a, b, acc[ft], 0, 0, 0);
    }
  }

  // epilogue 1: bias1 + relu + LN(g1, be1) -> T (into Ab)
  {
    float bb[8], gg[8], bee[8];
#pragma unroll
    for (int ft = 0; ft < 8; ++ft) {
      int f = ft*16 + l16;
      bb[ft] = b1[f]; gg[ft] = g1[f]; bee[ft] = be1[f];
    }
    float s1[4] = {0,0,0,0}, s2[4] = {0,0,0,0};
#pragma unroll
    for (int ft = 0; ft < 8; ++ft)
#pragma unroll
      for (int r = 0; r < 4; ++r) {
        float v = fmaxf(acc[ft][r] + bb[ft], 0.f);
        acc[ft][r] = v; s1[r] += v; s2[r] += v*v;
      }
#pragma unroll
    for (int m = 1; m < 16; m <<= 1)
#pragma unroll
      for (int r = 0; r < 4; ++r) {
        s1[r] += __shfl_xor(s1[r], m);
        s2[r] += __shfl_xor(s2[r], m);
      }
    float mu[4], rs[4];
#pragma unroll
    for (int r = 0; r < 4; ++r) {
      mu[r] = s1[r] * (1.f/128.f);
      float var = fmaxf(s2[r] * (1.f/128.f) - mu[r]*mu[r], 0.f);
      rs[r] = rsqrtf(var + LN_EPSF);
    }
    __syncthreads();
#pragma unroll
    for (int r = 0; r < 4; ++r) {
      int nloc = wv*16 + quad*4 + r;
#pragma unroll
      for (int ft = 0; ft < 8; ++ft) {
        float o = (acc[ft][r] - mu[r])*rs[r]*gg[ft] + bee[ft];
        Ab[nloc*136 + ft*16 + l16] = f2bf(o);
      }
    }
  }
  __syncthreads();

  // MFMA loop 2: T @ W2^T  (B from global)
#pragma unroll
  for (int ft = 0; ft < 8; ++ft) acc[ft] = (f32x4){0.f,0.f,0.f,0.f};
#pragma unroll
  for (int ks = 0; ks < 4; ++ks) {
    bf16x8 a = *(const bf16x8*)(const void*)&Ab[arow + ks*32];
#pragma unroll
    for (int ft = 0; ft < 8; ++ft) {
      bf16x8 b = *(const bf16x8*)&W2b[brow_base + ft*16*HIDC + ks*32];
      acc[ft] = __builtin_amdgcn_mfma_f32_16x16x32_bf16(a, b, acc[ft], 0, 0, 0);
    }
  }

  // epilogue 2: bias2 + relu + LN(lng, lnb) -> Ab
  {
    float bb[8], gg[8], bee[8];
#pragma unroll
    for (int ft = 0; ft < 8; ++ft) {
      int f = ft*16 + l16;
      bb[ft] = b2[f]; gg[ft] = lng[f]; bee[ft] = lnb[f];
    }
    float s1[4] = {0,0,0,0}, s2[4] = {0,0,0,0};
#pragma unroll
    for (int ft = 0; ft < 8; ++ft)
#pragma unroll
      for (int r = 0; r < 4; ++r) {
        float v = fmaxf(acc[ft][r] + bb[ft], 0.f);
        acc[ft][r] = v; s1[r] += v; s2[r] += v*v;
      }
#pragma unroll
    for (int m = 1; m < 16; m <<= 1)
#pragma unroll
      for (int r = 0; r < 4; ++r) {
        s1[r] += __shfl_xor(s1[r], m);
        s2[r] += __shfl_xor(s2[r], m);
      }
    float mu[4], rs[4];
#pragma unroll
    for (int r = 0; r < 4; ++r) {
      mu[r] = s1[r] * (1.f/128.f);
      float var = fmaxf(s2[r] * (1.f/128.f) - mu[r]*mu[r], 0.f);
      rs[r] = rsqrtf(var + LN_EPSF);
    }
    __syncthreads();
#pragma unroll
    for (int r = 0; r < 4; ++r) {
      int nloc = wv*16 + quad*4 + r;
#pragma unroll
      for (int ft = 0; ft < 8; ++ft) {
        float o = (acc[ft][r] - mu[r])*rs[r]*gg[ft] + bee[ft];
        Ab[nloc*136 + ft*16 + l16] = f2bf(o);
      }
    }
  }
  __syncthreads();
  // final store: + residual (Hin row), coalesced 16B chunks
#pragma unroll
  for (int i = 0; i < 4; ++i) {
    int chunk = t + i*256;
    int n = chunk >> 4, cc = chunk & 15;
    int gn = nb + n;
    if (gn >= N_NODESC) continue;
    bf16x8 vv = *(const bf16x8*)&Ab[n*136 + cc*8];
    bf16x8 rr = *(const bf16x8*)&Hin[gn*HIDC + cc*8];
    bf16x8 o8;
#pragma unroll
    for (int k = 0; k < 8; ++k)
      o8[k] = (short)f2bf(bf2f((unsigned short)vv[k]) + bf2f((unsigned short)rr[k]));
    *(bf16x8*)&Hout[gn*HIDC + cc*8] = o8;
  }
}

// ---------- MFMA gate (bf16 in, B from global) + inline per-graph max ----------
__global__ __launch_bounds__(256, 6) void gate_mfma_kernel(
    const unsigned short* __restrict__ Hb, const unsigned short* __restrict__ W1b,
    const float* __restrict__ b1, const float* __restrict__ lng,
    const float* __restrict__ lnb, const float* __restrict__ W2,
    const float* __restrict__ b2, const int* __restrict__ batch,
    float* __restrict__ gateb, unsigned* __restrict__ gmaxu) {
  __shared__ unsigned short Ab[64*136];
  __shared__ unsigned sgm[N_GRAPHSC];
  const int t = threadIdx.x;
  const int nb = blockIdx.x * 64;
  if (t < N_GRAPHSC) sgm[t] = 0u;
#pragma unroll
  for (int i = 0; i < 4; ++i) {
    int chunk = t + i*256;
    int n = chunk >> 4, c8 = chunk & 15;
    int gn = nb + n;
    bf16x8 v = {0,0,0,0,0,0,0,0};
    if (gn < N_NODESC) v = *(const bf16x8*)&Hb[gn*HIDC + c8*8];
    *(bf16x8*)&Ab[n*136 + c8*8] = v;
  }
  __syncthreads();

  const int lane = t & 63, wv = t >> 6;
  const int quad = lane >> 4, l16 = lane & 15;
  f32x4 acc[4];
#pragma unroll
  for (int ft = 0; ft < 4; ++ft) acc[ft] = (f32x4){0.f,0.f,0.f,0.f};

  const int arow = (wv*16 + l16)*136 + quad*8;
  const int brow_base = l16*HIDC + quad*8;
#pragma unroll
  for (int ks = 0; ks < 4; ++ks) {
    bf16x8 a = *(const bf16x8*)(const void*)&Ab[arow + ks*32];
#pragma unroll
    for (int ft = 0; ft < 4; ++ft) {
      bf16x8 b = *(const bf16x8*)&W1b[brow_base + ft*16*HIDC + ks*32];
      acc[ft] = __builtin_amdgcn_mfma_f32_16x16x32_bf16(a, b, acc[ft], 0, 0, 0);
    }
  }

  float bb[4], gg[4], bee[4], w2v[4];
#pragma unroll
  for (int ft = 0; ft < 4; ++ft) {
    int f = ft*16 + l16;
    bb[ft] = b1[f]; gg[ft] = lng[f]; bee[ft] = lnb[f]; w2v[ft] = W2[f];
  }
  float s1[4] = {0,0,0,0}, s2[4] = {0,0,0,0};
#pragma unroll
  for (int ft = 0; ft < 4; ++ft)
#pragma unroll
    for (int r = 0; r < 4; ++r) {
      float v = fmaxf(acc[ft][r] + bb[ft], 0.f);
      acc[ft][r] = v; s1[r] += v; s2[r] += v*v;
    }
#pragma unroll
  for (int m = 1; m < 16; m <<= 1)
#pragma unroll
    for (int r = 0; r < 4; ++r) {
      s1[r] += __shfl_xor(s1[r], m);
      s2[r] += __shfl_xor(s2[r], m);
    }
  float pd[4];
#pragma unroll
  for (int r = 0; r < 4; ++r) {
    float mu = s1[r] * (1.f/64.f);
    float var = fmaxf(s2[r] * (1.f/64.f) - mu*mu, 0.f);
    float rs = rsqrtf(var + LN_EPSF);
    float p = 0.f;
#pragma unroll
    for (int ft = 0; ft < 4; ++ft)
      p += ((acc[ft][r] - mu)*rs*gg[ft] + bee[ft]) * w2v[ft];
    pd[r] = p;
  }
#pragma unroll
  for (int m = 1; m < 16; m <<= 1)
#pragma unroll
    for (int r = 0; r < 4; ++r) pd[r] += __shfl_xor(pd[r], m);
  if (l16 == 0) {
    float b2v = b2[0];
#pragma unroll
    for (int r = 0; r < 4; ++r) {
      int node = nb + wv*16 + quad*4 + r;
      if (node < N_NODESC) {
        float gv = pd[r] + b2v;
        gateb[node] = gv;
        atomicMax(&sgm[batch[node]], ord_enc(gv));
      }
    }
  }
  __syncthreads();
  if (t < N_GRAPHSC && sgm[t] != 0u) atomicMax(&gmaxu[t], sgm[t]);
}

// ---------- segmented softmax-weighted pooling (bf16 H) ----------
__global__ __launch_bounds__(256) void pool_kernel(const unsigned short* __restrict__ Hb,
    const float* __restrict__ gateb, const int* __restrict__ gstart,
    const unsigned* __restrict__ gmaxu, float* __restrict__ S,
    float* __restrict__ denom) {
  const int g    = blockIdx.x / POOL_SPLIT;
  const int part = blockIdx.x % POOL_SPLIT;
  const int s0 = gstart[g], s1 = gstart[g+1];
  const int cnt = s1 - s0;
  const int chunk = (cnt + POOL_SPLIT - 1) / POOL_SPLIT;
  int lo = s0 + part * chunk;
  int hi = lo + chunk; if (hi > s1) hi = s1;
  const int t = threadIdx.x;
  const int c8 = t & 15;
  const int v  = t >> 4;
  const float gm = ord_dec(gmaxu[g]);
  float acc[8];
#pragma unroll
  for (int k = 0; k < 8; ++k) acc[k] = 0.f;
  float de = 0.f;
  for (int n = lo + v; n < hi; n += 16) {
    float e = expf(gateb[n] - gm);
    bf16x8 hv = *(const bf16x8*)&Hb[n*HIDC + c8*8];
#pragma unroll
    for (int k = 0; k < 8; ++k) acc[k] += e * bf2f((unsigned short)hv[k]);
    if (c8 == 0) de += e;
  }
  __shared__ float sacc[16*128];
  __shared__ float sden[16];
#pragma unroll
  for (int k = 0; k < 8; ++k) sacc[v*128 + c8*8 + k] = acc[k];
  if (c8 == 0) sden[v] = de;
  __syncthreads();
  if (t < 128) {
    float s = 0.f;
#pragma unroll
    for (int vv = 0; vv < 16; ++vv) s += sacc[vv*128 + t];
    atomicAdd(&S[g*HIDC + t], s);
  }
  if (t == 0) {
    float d = 0.f;
#pragma unroll
    for (int vv = 0; vv < 16; ++vv) d += sden[vv];
    atomicAdd(&denom[g], d);
  }
}

// ---------- head MLP per graph ----------
__global__ __launch_bounds__(64) void head_kernel(const float* __restrict__ S,
    const float* __restrict__ denom, const float* __restrict__ W1,
    const float* __restrict__ b1, const float* __restrict__ g,
    const float* __restrict__ be, const float* __restrict__ W2,
    const float* __restrict__ b2, float* __restrict__ out) {
  const int gr = blockIdx.x;
  const int j = threadIdx.x;
  const float inv = 1.0f / denom[gr];
  float v = b1[j];
  for (int k = 0; k < HIDC; ++k) v += (S[gr*HIDC + k] * inv) * W1[j*HIDC + k];
  v = fmaxf(v, 0.f);
  float s1 = v, s2 = v*v;
  for (int off = 32; off; off >>= 1) { s1 += __shfl_xor(s1, off); s2 += __shfl_xor(s2, off); }
  float mu = s1 * (1.f/64.f);
  float var = fmaxf(s2 * (1.f/64.f) - mu*mu, 0.f);
  float rs = rsqrtf(var + LN_EPSF);
  float z = (v-mu)*rs*g[j] + be[j];
  float p = z * W2[j];
  for (int off = 32; off; off >>= 1) p += __shfl_xor(p, off);
  if (j == 0) out[gr] = p + b2[0];
}

// ---------- launch ----------
extern "C" void kernel_launch(void* const* d_in, const int* in_sizes, int n_in,
                              void* d_out, int out_size, void* d_ws, size_t ws_size,
                              hipStream_t stream) {
  (void)in_sizes; (void)n_in; (void)out_size; (void)ws_size;
  const float* x     = (const float*)d_in[0];
  const int*   ei    = (const int*)d_in[1];
  const int*   batch = (const int*)d_in[2];
  const float* aW1 = (const float*)d_in[3];
  const float* ab1 = (const float*)d_in[4];
  const float* ag  = (const float*)d_in[5];
  const float* abe = (const float*)d_in[6];
  const float* aW2 = (const float*)d_in[7];
  const float* ab2 = (const float*)d_in[8];
  const float* oW1 = (const float*)d_in[9];
  const float* ob1 = (const float*)d_in[10];
  const float* og  = (const float*)d_in[11];
  const float* obe = (const float*)d_in[12];
  const float* oW2 = (const float*)d_in[13];
  const float* ob2 = (const float*)d_in[14];
  const float* ninW = (const float*)d_in[15];
  const float* ninb = (const float*)d_in[16];
  const float* cW1 = (const float*)d_in[17];
  const float* cb1 = (const float*)d_in[18];
  const float* cg  = (const float*)d_in[19];
  const float* cbe = (const float*)d_in[20];
  const float* cW2 = (const float*)d_in[21];
  const float* cb2 = (const float*)d_in[22];
  const float* eps = (const float*)d_in[23];
  const float* lng = (const float*)d_in[24];
  const float* lnb = (const float*)d_in[25];
  const float* gW1 = (const float*)d_in[26];
  const float* gb1 = (const float*)d_in[27];
  const float* gg  = (const float*)d_in[28];
  const float* gbe = (const float*)d_in[29];
  const float* gW2 = (const float*)d_in[30];
  const float* gb2 = (const float*)d_in[31];
  const float* hW1 = (const float*)d_in[32];
  const float* hb1 = (const float*)d_in[33];
  const float* hg  = (const float*)d_in[34];
  const float* hbe = (const float*)d_in[35];
  const float* hW2 = (const float*)d_in[36];
  const float* hb2 = (const float*)d_in[37];

  char* ws = (char*)d_ws;
  unsigned short* Ha = (unsigned short*)(ws + 0);          // 12,800,000 B
  unsigned short* Hc = (unsigned short*)(ws + 12800000);   // 12,800,000 B
  float* gateb = (float*)(ws + 25600000);                  // 200,000 B
  // --- contiguous zero region: deg | S | denom | gmaxu ---
  int*   deg   = (int*)(ws + 25800000);                    // 200,000 B
  float* S     = (float*)(ws + 26000000);                  // 32,768 B
  float* denom = (float*)(ws + 26032768);                  // 256 B
  unsigned* gmaxu = (unsigned*)(ws + 26033024);            // 256 B
  // -------------------------------------------------------
  int* rowptr  = (int*)(ws + 26033280);                    // 200,004 B
  int* cursor  = (int*)(ws + 26233284);                    // 200,000 B
  int* esrc    = (int*)(ws + 26433284);                    // 2,560,000 B
  int* bsum    = (int*)(ws + 28993284);                    // 256 B
  int* gstart  = (int*)(ws + 28993540);                    // 260 B
  unsigned short* Wb1 = (unsigned short*)(ws + 29000000);  // 98,304 B (3 x 128x128 bf16)
  unsigned short* Wb2 = (unsigned short*)(ws + 29100000);  // 98,304 B
  unsigned short* gWb = (unsigned short*)(ws + 29200000);  // 16,384 B

  hipMemsetAsync(deg, 0, 233280, stream);  // deg + S + denom + gmaxu

  wprep_kernel<<<(106496 + 255) / 256, 256, 0, stream>>>(cW1, cW2, gW1, Wb1, Wb2, gWb);
  hist_gbound_kernel<<<EGRID + NGRID_GB, 256, 0, stream>>>(ei, deg, batch, gstart);
  scan1_kernel<<<SCAN_NB, 1024, 0, stream>>>(deg, rowptr, bsum);
  scan23_kernel<<<SCAN_NB, 1024, 0, stream>>>(deg, bsum, rowptr, cursor);
  scatter_kernel<<<EGRID, 256, 0, stream>>>(ei, cursor, esrc);

  const int ngrid64 = (N_NODESC + 63) / 64;
  enc_kernel<<<ngrid64, 128, 0, stream>>>(x, aW1, ab1, ag, abe, aW2, ab2,
                                          oW1, ob1, og, obe, oW2, ob2,
                                          ninW, ninb, Ha);
  unsigned short* cur = Ha;
  unsigned short* nxt = Hc;
  for (int l = 0; l < 3; ++l) {
    conv_fused_kernel<<<ngrid64, 256, 0, stream>>>(
        cur, rowptr, esrc, eps + l,
        Wb1 + l*HIDC*HIDC, cb1 + l*HIDC, cg + l*HIDC, cbe + l*HIDC,
        Wb2 + l*HIDC*HIDC, cb2 + l*HIDC, lng + l*HIDC, lnb + l*HIDC,
        nxt);
    unsigned short* tmp = cur; cur = nxt; nxt = tmp;
  }
  // after 3 layers, cur == Hc holds the final H
  gate_mfma_kernel<<<ngrid64, 256, 0, stream>>>(cur, gWb, gb1, gg, gbe, gW2, gb2,
                                                batch, gateb, gmaxu);
  pool_kernel<<<N_GRAPHSC * POOL_SPLIT, 256, 0, stream>>>(cur, gateb, gstart, gmaxu, S, denom);
  head_kernel<<<N_GRAPHSC, 64, 0, stream>>>(S, denom, hW1, hb1, hg, hbe, hW2, hb2,
                                            (float*)d_out);
}